// Round 1
// baseline (102.272 us; speedup 1.0000x reference)
//
#include <hip/hip_runtime.h>
#include <hip/hip_bf16.h>
#include <stdint.h>

#define NUM_SPARSE 26
#define VOCAB 100000
#define EMB 128
#define ROWS 32

typedef __attribute__((ext_vector_type(8))) short bf16x8;
typedef __attribute__((ext_vector_type(16))) float f32x16;

__device__ __forceinline__ unsigned short f2bf(float x) {
    union { float f; uint32_t u; } v; v.f = x;
    uint32_t u = v.u;
    return (unsigned short)((u + 0x7FFFu + ((u >> 16) & 1u)) >> 16);  // RNE
}
__device__ __forceinline__ uint32_t pack2bf(float a, float b) {
    return (uint32_t)f2bf(a) | ((uint32_t)f2bf(b) << 16);
}

// swizzled byte offset for bf16 element (row r, col c) in a row of `rowbytes`
// (16B slots XOR'd with low 4 bits of row -> ds_read_b128 A-frags ~conflict-free)
__device__ __forceinline__ int swz(int r, int c, int rowbytes) {
    int b = 2 * c;
    return r * rowbytes + (((b >> 4) ^ (r & 15)) << 4) + (b & 15);
}
// A-fragment read: 8 bf16 at (row m, k0..k0+7), k0 multiple of 8
__device__ __forceinline__ bf16x8 ldsA(const char* base, int m, int k0, int rowbytes) {
    int slot = (k0 >> 3) ^ (m & 15);
    return *(const bf16x8*)(base + m * rowbytes + slot * 16);
}

// ws layout (bf16): [0,32768): bw2_t[128][256]; [32768,94208): tw1_t[128][480]; [94208,102400): tw2_t[64][128]
__global__ void prep_weights(const float* __restrict__ bw2, const float* __restrict__ tw1,
                             const float* __restrict__ tw2, unsigned short* __restrict__ ws) {
    int i = blockIdx.x * blockDim.x + threadIdx.x;
    if (i < 128 * 256) {
        int n = i >> 8, k = i & 255;
        ws[i] = f2bf(bw2[k * 128 + n]);
    } else if (i < 128 * 256 + 128 * 480) {
        int j = i - 128 * 256;
        int n = j / 480, k = j - n * 480;
        ws[i] = f2bf(k < 479 ? tw1[k * 128 + n] : 0.f);
    } else if (i < 128 * 256 + 128 * 480 + 64 * 128) {
        int j = i - (128 * 256 + 128 * 480);
        int n = j >> 7, k = j & 127;
        ws[i] = f2bf(tw2[k * 64 + n]);
    }
}

// LDS map (64 KB):
//  region A [0,32768): P1-P2: xd fp32[416]@0, h bf16[32][512B]@2048
//                      P3:    C_lds per wave @ w*8192, [32][256B]
//                      P4-P6: t1 bf16[32][256B]@0, t2 fp32[32][65]@8192
//  region B [32768,65536): x_final bf16 [32][1024B]  (cols 0..478 real, 479..511 zero)
__global__ __launch_bounds__(256, 2) void dlrm_main(
    const float* __restrict__ dense, const int* __restrict__ sparse,
    const float* __restrict__ emb, const float* __restrict__ bw1,
    const float* __restrict__ bb1, const float* __restrict__ bb2,
    const float* __restrict__ tb1, const float* __restrict__ tb2,
    const float* __restrict__ tw3, const float* __restrict__ tb3,
    const unsigned short* __restrict__ wsw, float* __restrict__ out)
{
    __shared__ __align__(16) char smem[65536];
    const int t = threadIdx.x;
    const int w = t >> 6;
    const int l = t & 63;
    const int hi = l >> 5;
    const int lm = l & 31;
    const int r0 = blockIdx.x * ROWS;

    float* xd = (float*)smem;
    char* xf = smem + 32768;

    // P0: stage dense tile + zero-pad x_final cols 479..511
    for (int i = t; i < ROWS * 13; i += 256) xd[i] = dense[r0 * 13 + i];
    for (int i = t; i < ROWS * 33; i += 256) {
        int r = i / 33, c = 479 + (i - r * 33);
        *(unsigned short*)(xf + swz(r, c, 1024)) = 0;
    }
    __syncthreads();

    // P1: h = relu(dense @ bw1 + bb1), thread t owns output column j=t
    {
        char* hb = smem + 2048;
        int j = t;
        float w1r[13];
#pragma unroll
        for (int k = 0; k < 13; k++) w1r[k] = bw1[k * 256 + j];
        float b = bb1[j];
        for (int r = 0; r < ROWS; r++) {
            float acc = b;
#pragma unroll
            for (int k = 0; k < 13; k++) acc += xd[r * 13 + k] * w1r[k];
            *(unsigned short*)(hb + swz(r, j, 512)) = f2bf(fmaxf(acc, 0.f));
        }
    }
    __syncthreads();

    // P2: x_bottom = relu(h @ bw2 + bb2) via MFMA; write bf16 into x_final cols 0..127
    {
        const char* hb = smem + 2048;
        const unsigned short* bw2t = wsw;
        int n0 = w * 32;
        f32x16 acc = {0,0,0,0,0,0,0,0,0,0,0,0,0,0,0,0};
#pragma unroll
        for (int kk = 0; kk < 16; kk++) {
            int k0 = kk * 16 + hi * 8;
            bf16x8 a = ldsA(hb, lm, k0, 512);
            bf16x8 b = *(const bf16x8*)(bw2t + (n0 + lm) * 256 + k0);
            acc = __builtin_amdgcn_mfma_f32_32x32x16_bf16(a, b, acc, 0, 0, 0);
        }
        float bias = bb2[n0 + lm];
#pragma unroll
        for (int reg = 0; reg < 16; reg++) {
            int m = (reg & 3) + 8 * (reg >> 2) + 4 * hi;
            float v = fmaxf(acc[reg] + bias, 0.f);
            *(unsigned short*)(xf + swz(m, n0 + lm, 1024)) = f2bf(v);
        }
    }
    __syncthreads();

    // P3: per-wave gather + gram (rows w*8 .. w*8+7)
    {
        char* Cb = smem + w * 8192;   // [32 fields][256B], field rows swizzled
        for (int ri = 0; ri < 8; ri++) {
            int r = w * 8 + ri;
            int myidx = (l < NUM_SPARSE) ? sparse[(size_t)(r0 + r) * NUM_SPARSE + l] : 0;
            // field 0 = x_bottom (already bf16 in x_final)
            {
                uint32_t v = *(const uint32_t*)(xf + swz(r, 2 * l, 1024));
                *(uint32_t*)(Cb + 4 * l) = v;   // row 0, swizzle is identity for r=0
            }
            // fields 1..26: 2 fields per dwordx4 (lanes 0-31 field 2i, 32-63 field 2i+1)
            float4 buf[13];
#pragma unroll
            for (int i = 0; i < 13; i++) {
                int fld = 2 * i + hi;                 // 0..25
                int idx = __shfl(myidx, fld);
                buf[i] = *(const float4*)(emb + ((size_t)fld * VOCAB + (size_t)idx) * EMB + 4 * lm);
            }
#pragma unroll
            for (int i = 0; i < 13; i++) {
                int frow = 1 + 2 * i + hi;
                uint32_t p0 = pack2bf(buf[i].x, buf[i].y);
                uint32_t p1 = pack2bf(buf[i].z, buf[i].w);
                char* dst = Cb + frow * 256 + ((((lm >> 1) ^ (frow & 15))) << 4) + (lm & 1) * 8;
                *(uint32_t*)dst = p0;
                *(uint32_t*)(dst + 4) = p1;
            }
            // gram: D = C * C^T  (A-frag == B-frag for symmetric product)
            f32x16 acc = {0,0,0,0,0,0,0,0,0,0,0,0,0,0,0,0};
#pragma unroll
            for (int kk = 0; kk < 8; kk++) {
                int k0 = kk * 16 + hi * 8;
                bf16x8 a = ldsA(Cb, lm, k0, 256);
                acc = __builtin_amdgcn_mfma_f32_32x32x16_bf16(a, a, acc, 0, 0, 0);
            }
            // extract upper triangle (m<n<=26) -> x_final cols 128..478
            int n = lm;
            if (n >= 1 && n <= 26) {
#pragma unroll
                for (int reg = 0; reg < 16; reg++) {
                    int m = (reg & 3) + 8 * (reg >> 2) + 4 * hi;
                    if (m < n) {
                        int p = 26 * m - (m * (m - 1)) / 2 + (n - m - 1);
                        *(unsigned short*)(xf + swz(r, 128 + p, 1024)) = f2bf(acc[reg]);
                    }
                }
            }
        }
    }
    __syncthreads();

    // P4: t1 = relu(x_final @ tw1 + tb1) via MFMA (K=480, zero-padded)
    {
        const unsigned short* tw1t = wsw + 32768;
        int n0 = w * 32;
        f32x16 acc = {0,0,0,0,0,0,0,0,0,0,0,0,0,0,0,0};
#pragma unroll
        for (int kk = 0; kk < 30; kk++) {
            int k0 = kk * 16 + hi * 8;
            bf16x8 a = ldsA(xf, lm, k0, 1024);
            bf16x8 b = *(const bf16x8*)(tw1t + (n0 + lm) * 480 + k0);
            acc = __builtin_amdgcn_mfma_f32_32x32x16_bf16(a, b, acc, 0, 0, 0);
        }
        float bias = tb1[n0 + lm];
#pragma unroll
        for (int reg = 0; reg < 16; reg++) {
            int m = (reg & 3) + 8 * (reg >> 2) + 4 * hi;
            float v = fmaxf(acc[reg] + bias, 0.f);
            *(unsigned short*)(smem + swz(m, n0 + lm, 256)) = f2bf(v);  // t1 @ 0
        }
    }
    __syncthreads();

    // P5: t2 = relu(t1 @ tw2 + tb2) -> fp32 LDS [32][65] @ 8192 (waves 0,1)
    float* t2b = (float*)(smem + 8192);
    if (w < 2) {
        const unsigned short* tw2t = wsw + 32768 + 61440;
        int n0 = w * 32;
        f32x16 acc = {0,0,0,0,0,0,0,0,0,0,0,0,0,0,0,0};
#pragma unroll
        for (int kk = 0; kk < 8; kk++) {
            int k0 = kk * 16 + hi * 8;
            bf16x8 a = ldsA(smem, lm, k0, 256);
            bf16x8 b = *(const bf16x8*)(tw2t + (n0 + lm) * 128 + k0);
            acc = __builtin_amdgcn_mfma_f32_32x32x16_bf16(a, b, acc, 0, 0, 0);
        }
        float bias = tb2[n0 + lm];
#pragma unroll
        for (int reg = 0; reg < 16; reg++) {
            int m = (reg & 3) + 8 * (reg >> 2) + 4 * hi;
            t2b[m * 65 + n0 + lm] = fmaxf(acc[reg] + bias, 0.f);
        }
    }
    __syncthreads();

    // P6: logits + sigmoid
    if (t < ROWS) {
        float acc = tb3[0];
#pragma unroll
        for (int k = 0; k < 64; k++) acc += t2b[t * 65 + k] * tw3[k];
        out[r0 + t] = 1.f / (1.f + expf(-acc));
    }
}

extern "C" void kernel_launch(void* const* d_in, const int* in_sizes, int n_in,
                              void* d_out, int out_size, void* d_ws, size_t ws_size,
                              hipStream_t stream) {
    const float* dense = (const float*)d_in[0];
    const int*   sparse = (const int*)d_in[1];
    const float* emb   = (const float*)d_in[2];
    const float* bw1   = (const float*)d_in[3];
    const float* bb1   = (const float*)d_in[4];
    const float* bw2   = (const float*)d_in[5];
    const float* bb2   = (const float*)d_in[6];
    const float* tw1   = (const float*)d_in[7];
    const float* tb1   = (const float*)d_in[8];
    const float* tw2   = (const float*)d_in[9];
    const float* tb2   = (const float*)d_in[10];
    const float* tw3   = (const float*)d_in[11];
    const float* tb3   = (const float*)d_in[12];
    unsigned short* wsw = (unsigned short*)d_ws;
    float* out = (float*)d_out;

    hipLaunchKernelGGL(prep_weights, dim3(400), dim3(256), 0, stream, bw2, tw1, tw2, wsw);
    hipLaunchKernelGGL(dlrm_main, dim3(32768 / ROWS), dim3(256), 0, stream,
                       dense, sparse, emb, bw1, bb1, bb2, tb1, tb2, tw3, tb3, wsw, out);
}

// Round 2
// 96.545 us; speedup vs baseline: 1.0593x; 1.0593x over previous
//
#include <hip/hip_runtime.h>
#include <hip/hip_bf16.h>
#include <stdint.h>

#define NUM_SPARSE 26
#define VOCAB 100000
#define EMB 128
#define ROWS 32

typedef __attribute__((ext_vector_type(8))) short bf16x8;
typedef __attribute__((ext_vector_type(16))) float f32x16;

__device__ __forceinline__ unsigned short f2bf(float x) {
    union { float f; uint32_t u; } v; v.f = x;
    uint32_t u = v.u;
    return (unsigned short)((u + 0x7FFFu + ((u >> 16) & 1u)) >> 16);  // RNE
}
__device__ __forceinline__ uint32_t pack2bf(float a, float b) {
    return (uint32_t)f2bf(a) | ((uint32_t)f2bf(b) << 16);
}

// swizzled byte offset for bf16 element (row r, col c) in a row of `rowbytes`
// (16B slots XOR'd with low 4 bits of row -> ds_read_b128 A-frags ~conflict-free)
__device__ __forceinline__ int swz(int r, int c, int rowbytes) {
    int b = 2 * c;
    return r * rowbytes + (((b >> 4) ^ (r & 15)) << 4) + (b & 15);
}
// A-fragment read: 8 bf16 at (row m, k0..k0+7), k0 multiple of 8
__device__ __forceinline__ bf16x8 ldsA(const char* base, int m, int k0, int rowbytes) {
    int slot = (k0 >> 3) ^ (m & 15);
    return *(const bf16x8*)(base + m * rowbytes + slot * 16);
}

// ws layout (bf16): [0,32768): bw2_t[128][256]; [32768,94208): tw1_t[128][480]; [94208,102400): tw2_t[64][128]
__global__ void prep_weights(const float* __restrict__ bw2, const float* __restrict__ tw1,
                             const float* __restrict__ tw2, unsigned short* __restrict__ ws) {
    int i = blockIdx.x * blockDim.x + threadIdx.x;
    if (i < 128 * 256) {
        int n = i >> 8, k = i & 255;
        ws[i] = f2bf(bw2[k * 128 + n]);
    } else if (i < 128 * 256 + 128 * 480) {
        int j = i - 128 * 256;
        int n = j / 480, k = j - n * 480;
        ws[i] = f2bf(k < 479 ? tw1[k * 128 + n] : 0.f);
    } else if (i < 128 * 256 + 128 * 480 + 64 * 128) {
        int j = i - (128 * 256 + 128 * 480);
        int n = j >> 7, k = j & 127;
        ws[i] = f2bf(tw2[k * 64 + n]);
    }
}

// LDS map (64 KB):
//  region A [0,32768): P1-P2: xd fp32[416]@0, h bf16[32][512B]@2048
//                      P3:    C_lds per wave @ w*8192, [32][256B]
//                      P4-P6: t1 bf16[32][256B]@0, t2 fp32[32][65]@8192
//  region B [32768,65536): x_final bf16 [32][1024B]  (cols 0..478 real, 479..511 zero)
__global__ __launch_bounds__(256, 2) void dlrm_main(
    const float* __restrict__ dense, const int* __restrict__ sparse,
    const float* __restrict__ emb, const float* __restrict__ bw1,
    const float* __restrict__ bb1, const float* __restrict__ bb2,
    const float* __restrict__ tb1, const float* __restrict__ tb2,
    const float* __restrict__ tw3, const float* __restrict__ tb3,
    const unsigned short* __restrict__ wsw, float* __restrict__ out)
{
    __shared__ __align__(16) char smem[65536];
    const int t = threadIdx.x;
    const int w = t >> 6;
    const int l = t & 63;
    const int hi = l >> 5;
    const int lm = l & 31;
    const int r0 = blockIdx.x * ROWS;

    float* xd = (float*)smem;
    char* xf = smem + 32768;

    // Hoisted: per-lane sparse indices for this wave's 8 rows (kills per-row
    // index->gather latency chain; issued before any compute).
    int idxs[8];
#pragma unroll
    for (int ri = 0; ri < 8; ri++)
        idxs[ri] = (l < NUM_SPARSE)
            ? sparse[(size_t)(r0 + w * 8 + ri) * NUM_SPARSE + l] : 0;

    // P0: stage dense tile + zero-pad x_final cols 479..511
    for (int i = t; i < ROWS * 13; i += 256) xd[i] = dense[r0 * 13 + i];
    for (int i = t; i < ROWS * 33; i += 256) {
        int r = i / 33, c = 479 + (i - r * 33);
        *(unsigned short*)(xf + swz(r, c, 1024)) = 0;
    }

    // Issue row-0 gather NOW: its ~900cy HBM latency hides under P1/P2 compute.
    float4 bufA[13], bufB[13];
#pragma unroll
    for (int i = 0; i < 13; i++) {
        int fld = 2 * i + hi;
        int idx = __shfl(idxs[0], fld);
        bufA[i] = *(const float4*)(emb + ((size_t)fld * VOCAB + (size_t)idx) * EMB + 4 * lm);
    }
    __syncthreads();

    // P1: h = relu(dense @ bw1 + bb1), thread t owns output column j=t
    {
        char* hb = smem + 2048;
        int j = t;
        float w1r[13];
#pragma unroll
        for (int k = 0; k < 13; k++) w1r[k] = bw1[k * 256 + j];
        float b = bb1[j];
        for (int r = 0; r < ROWS; r++) {
            float acc = b;
#pragma unroll
            for (int k = 0; k < 13; k++) acc += xd[r * 13 + k] * w1r[k];
            *(unsigned short*)(hb + swz(r, j, 512)) = f2bf(fmaxf(acc, 0.f));
        }
    }
    __syncthreads();

    // P2: x_bottom = relu(h @ bw2 + bb2) via MFMA; write bf16 into x_final cols 0..127
    {
        const char* hb = smem + 2048;
        const unsigned short* bw2t = wsw;
        int n0 = w * 32;
        f32x16 acc = {0,0,0,0,0,0,0,0,0,0,0,0,0,0,0,0};
#pragma unroll
        for (int kk = 0; kk < 16; kk++) {
            int k0 = kk * 16 + hi * 8;
            bf16x8 a = ldsA(hb, lm, k0, 512);
            bf16x8 b = *(const bf16x8*)(bw2t + (n0 + lm) * 256 + k0);
            acc = __builtin_amdgcn_mfma_f32_32x32x16_bf16(a, b, acc, 0, 0, 0);
        }
        float bias = bb2[n0 + lm];
#pragma unroll
        for (int reg = 0; reg < 16; reg++) {
            int m = (reg & 3) + 8 * (reg >> 2) + 4 * hi;
            float v = fmaxf(acc[reg] + bias, 0.f);
            *(unsigned short*)(xf + swz(m, n0 + lm, 1024)) = f2bf(v);
        }
    }
    __syncthreads();

    // P3: per-wave gather + gram (rows w*8 .. w*8+7), 2-row software pipeline.
    // Static bufA/bufB parity (loop fully unrolled) keeps arrays in VGPRs.
    {
        char* Cb = smem + w * 8192;   // [32 fields][256B], field rows swizzled
#pragma unroll
        for (int ri = 0; ri < 8; ri++) {
            // issue next row's gathers before consuming current row
            if (ri < 7) {
#pragma unroll
                for (int i = 0; i < 13; i++) {
                    int fld = 2 * i + hi;
                    int idx = __shfl(idxs[ri + 1], fld);
                    float4 v = *(const float4*)(emb + ((size_t)fld * VOCAB + (size_t)idx) * EMB + 4 * lm);
                    if (ri & 1) bufA[i] = v; else bufB[i] = v;
                }
            }
            int r = w * 8 + ri;
            // field 0 = x_bottom (already bf16 in x_final)
            {
                uint32_t v = *(const uint32_t*)(xf + swz(r, 2 * l, 1024));
                *(uint32_t*)(Cb + 4 * l) = v;   // row 0, swizzle is identity for r=0
            }
            // fields 1..26: 2 fields per dwordx4 (lanes 0-31 field 2i, 32-63 field 2i+1)
#pragma unroll
            for (int i = 0; i < 13; i++) {
                float4 bv = (ri & 1) ? bufB[i] : bufA[i];
                int frow = 1 + 2 * i + hi;
                uint32_t p0 = pack2bf(bv.x, bv.y);
                uint32_t p1 = pack2bf(bv.z, bv.w);
                char* dst = Cb + frow * 256 + ((((lm >> 1) ^ (frow & 15))) << 4) + (lm & 1) * 8;
                *(uint32_t*)dst = p0;
                *(uint32_t*)(dst + 4) = p1;
            }
            // gram: D = C * C^T  (A-frag == B-frag for symmetric product)
            f32x16 acc = {0,0,0,0,0,0,0,0,0,0,0,0,0,0,0,0};
#pragma unroll
            for (int kk = 0; kk < 8; kk++) {
                int k0 = kk * 16 + hi * 8;
                bf16x8 a = ldsA(Cb, lm, k0, 256);
                acc = __builtin_amdgcn_mfma_f32_32x32x16_bf16(a, a, acc, 0, 0, 0);
            }
            // extract upper triangle (m<n<=26) -> x_final cols 128..478
            int n = lm;
            if (n >= 1 && n <= 26) {
#pragma unroll
                for (int reg = 0; reg < 16; reg++) {
                    int m = (reg & 3) + 8 * (reg >> 2) + 4 * hi;
                    if (m < n) {
                        int p = 26 * m - (m * (m - 1)) / 2 + (n - m - 1);
                        *(unsigned short*)(xf + swz(r, 128 + p, 1024)) = f2bf(acc[reg]);
                    }
                }
            }
        }
    }
    __syncthreads();

    // P4: t1 = relu(x_final @ tw1 + tb1) via MFMA (K=480, zero-padded)
    {
        const unsigned short* tw1t = wsw + 32768;
        int n0 = w * 32;
        f32x16 acc = {0,0,0,0,0,0,0,0,0,0,0,0,0,0,0,0};
#pragma unroll
        for (int kk = 0; kk < 30; kk++) {
            int k0 = kk * 16 + hi * 8;
            bf16x8 a = ldsA(xf, lm, k0, 1024);
            bf16x8 b = *(const bf16x8*)(tw1t + (n0 + lm) * 480 + k0);
            acc = __builtin_amdgcn_mfma_f32_32x32x16_bf16(a, b, acc, 0, 0, 0);
        }
        float bias = tb1[n0 + lm];
#pragma unroll
        for (int reg = 0; reg < 16; reg++) {
            int m = (reg & 3) + 8 * (reg >> 2) + 4 * hi;
            float v = fmaxf(acc[reg] + bias, 0.f);
            *(unsigned short*)(smem + swz(m, n0 + lm, 256)) = f2bf(v);  // t1 @ 0
        }
    }
    __syncthreads();

    // P5: t2 = relu(t1 @ tw2 + tb2) -> fp32 LDS [32][65] @ 8192 (waves 0,1)
    float* t2b = (float*)(smem + 8192);
    if (w < 2) {
        const unsigned short* tw2t = wsw + 32768 + 61440;
        int n0 = w * 32;
        f32x16 acc = {0,0,0,0,0,0,0,0,0,0,0,0,0,0,0,0};
#pragma unroll
        for (int kk = 0; kk < 8; kk++) {
            int k0 = kk * 16 + hi * 8;
            bf16x8 a = ldsA(smem, lm, k0, 256);
            bf16x8 b = *(const bf16x8*)(tw2t + (n0 + lm) * 128 + k0);
            acc = __builtin_amdgcn_mfma_f32_32x32x16_bf16(a, b, acc, 0, 0, 0);
        }
        float bias = tb2[n0 + lm];
#pragma unroll
        for (int reg = 0; reg < 16; reg++) {
            int m = (reg & 3) + 8 * (reg >> 2) + 4 * hi;
            t2b[m * 65 + n0 + lm] = fmaxf(acc[reg] + bias, 0.f);
        }
    }
    __syncthreads();

    // P6: logits + sigmoid
    if (t < ROWS) {
        float acc = tb3[0];
#pragma unroll
        for (int k = 0; k < 64; k++) acc += t2b[t * 65 + k] * tw3[k];
        out[r0 + t] = 1.f / (1.f + expf(-acc));
    }
}

extern "C" void kernel_launch(void* const* d_in, const int* in_sizes, int n_in,
                              void* d_out, int out_size, void* d_ws, size_t ws_size,
                              hipStream_t stream) {
    const float* dense = (const float*)d_in[0];
    const int*   sparse = (const int*)d_in[1];
    const float* emb   = (const float*)d_in[2];
    const float* bw1   = (const float*)d_in[3];
    const float* bb1   = (const float*)d_in[4];
    const float* bw2   = (const float*)d_in[5];
    const float* bb2   = (const float*)d_in[6];
    const float* tw1   = (const float*)d_in[7];
    const float* tb1   = (const float*)d_in[8];
    const float* tw2   = (const float*)d_in[9];
    const float* tb2   = (const float*)d_in[10];
    const float* tw3   = (const float*)d_in[11];
    const float* tb3   = (const float*)d_in[12];
    unsigned short* wsw = (unsigned short*)d_ws;
    float* out = (float*)d_out;

    hipLaunchKernelGGL(prep_weights, dim3(400), dim3(256), 0, stream, bw2, tw1, tw2, wsw);
    hipLaunchKernelGGL(dlrm_main, dim3(32768 / ROWS), dim3(256), 0, stream,
                       dense, sparse, emb, bw1, bb1, bb2, tb1, tb2, tw3, tb3, wsw, out);
}